// Round 10
// baseline (789.112 us; speedup 1.0000x reference)
//
#include <hip/hip_runtime.h>

// DecoderRNN v10: 3-layer GRU, B=32768, H=100, 21 steps, VOCAB=20.
// Block = 8 waves x 64 batch rows, grid 512 (1 block/CU, 2 rounds).
// DOUBLE-BUFFERED h per layer (read H[p], write H[1-p], flip per t):
// kills the in-place read/write hazard -> immediate h writes, ONE barrier
// per phase, and each phase reads S once + D once (v9 read them 3x).
// Phase = pass X (Wi pinned 48 regs, gx accs parked f32 - AGPR spill ok)
//       + pass G (Wh pinned 48 regs, combine, write h to H[1-p]).
// LDS 112 KB static: X0 + 3 layers x 2 copies, [64][128] bf16 swizzled.
// Weights stream once per phase per wave from L2. Builtin MFMA only.

#define NTHR 512
#define NBLK 512
#define ROWS_PB 64
#define NGRP 4

// wp (u16) offsets
#define OFF_PROJ 0                 // [112][128]
#define OFF_IH0  14336             // each [336][128]: row g*112+nn, col 100 = bias
#define OFF_HH0  57344
#define OFF_IH1  100352
#define OFF_HH1  143360
#define OFF_IH2  186368
#define OFF_HH2  229376
#define OFF_OUT  272384            // [32][128], col 100 = b_out (rows 20..31 zero)
#define WP_TOTAL 276480

// LDS (u16): X0 + H[l][c] buffers, each [64][128] swizzled
#define X0_OFF   0
#define HB(l, c) (8192 * (1 + 2 * (l) + (c)))
#define SMEM_U16 57344             // 114688 B static

using frag8 = __attribute__((ext_vector_type(8))) short;
using frag4 = __attribute__((ext_vector_type(4))) short;
using f32x4 = __attribute__((ext_vector_type(4))) float;

struct G4 { frag8 a, b, c, d; };

__device__ __forceinline__ unsigned short f2b(float f) {
    union { float f; unsigned u; } v; v.f = f;
    unsigned r = v.u + 0x7FFF + ((v.u >> 16) & 1);   // RNE
    return (unsigned short)(r >> 16);
}
__device__ __forceinline__ float b2f(unsigned short b) {
    union { unsigned u; float f; } v; v.u = ((unsigned)b) << 16; return v.f;
}

__device__ __forceinline__ f32x4 mfma32(frag8 a, frag8 b, f32x4 c) {
    return __builtin_amdgcn_mfma_f32_16x16x32_bf16(a, b, c, 0, 0, 0);
}
__device__ __forceinline__ f32x4 dot4(const G4& w, const G4& s, f32x4 acc) {
    acc = mfma32(w.a, s.a, acc); acc = mfma32(w.b, s.b, acc);
    acc = mfma32(w.c, s.c, acc); return mfma32(w.d, s.d, acc);
}
// keep a loaded fragment opaque -> compiler cannot rematerialize its load
__device__ __forceinline__ void pin(G4& w) {
    asm volatile("" : "+v"(w.a), "+v"(w.b), "+v"(w.c), "+v"(w.d));
}

// ---------------- weight prep: f32 -> bf16, padded, bias col 100, prescaled ----
__global__ void prep_kernel(const float* __restrict__ w_proj,
    const float* __restrict__ wih0, const float* __restrict__ bih0,
    const float* __restrict__ whh0, const float* __restrict__ bhh0,
    const float* __restrict__ wih1, const float* __restrict__ bih1,
    const float* __restrict__ whh1, const float* __restrict__ bhh1,
    const float* __restrict__ wih2, const float* __restrict__ bih2,
    const float* __restrict__ whh2, const float* __restrict__ bhh2,
    const float* __restrict__ w_out, const float* __restrict__ b_out,
    unsigned short* __restrict__ dst)
{
    const float LOG2E  = 1.4426950408889634f;
    const float LOG2E2 = 2.8853900817779268f;
    int idx = blockIdx.x * 256 + threadIdx.x;
    if (idx >= WP_TOTAL) return;
    float v = 0.f;
    if (idx < OFF_IH0) {
        int n = idx >> 7, k = idx & 127;
        if (n < 100) v = w_proj[n * 128 + k];
    } else if (idx < OFF_OUT) {
        int r = idx - OFF_IH0;
        int mi = r / 43008;
        int e  = r - mi * 43008;
        int n = e >> 7, k = e & 127;
        int g = n / 112, nn = n - g * 112;
        if (nn < 100) {
            const float* W; const float* Bv;
            switch (mi) {
                case 0: W = wih0; Bv = bih0; break;
                case 1: W = whh0; Bv = bhh0; break;
                case 2: W = wih1; Bv = bih1; break;
                case 3: W = whh1; Bv = bhh1; break;
                case 4: W = wih2; Bv = bih2; break;
                default: W = whh2; Bv = bhh2; break;
            }
            if (k < 100) v = W[(g * 100 + nn) * 100 + k];
            else if (k == 100) v = Bv[g * 100 + nn];
            v *= (g == 2) ? LOG2E2 : LOG2E;       // exp2-form activations
        }
    } else {
        int e = idx - OFF_OUT;
        int n = e >> 7, k = e & 127;
        if (n < 20) {
            if (k < 100) v = w_out[n * 100 + k];
            else if (k == 100) v = b_out[n];
        }
    }
    dst[idx] = f2b(v);
}

// ---------------- LDS helpers (swizzled) ----------------
// logical u16 col cu of row r stored at 8-u16 chunk (cu>>3) ^ (r&7)
__device__ __forceinline__ int hsw(int buf, int grp, int r, int cu) {
    int row = grp * 16 + r;
    return buf + row * 128 + ((((cu >> 3) ^ (row & 7)) << 3) | (cu & 7));
}
__device__ __forceinline__ G4 ldSG4(const unsigned short* sm, int buf, int grp, int c16, int g4) {
    const unsigned short* p = sm + buf + (grp * 16 + c16) * 128;
    int x = c16 & 7;
    G4 s;
    s.a = *(const frag8*)(p + ((g4 ^ x) << 3));
    s.b = *(const frag8*)(p + (((4 + g4) ^ x) << 3));
    s.c = *(const frag8*)(p + (((8 + g4) ^ x) << 3));
    s.d = *(const frag8*)(p + (((12 + g4) ^ x) << 3));
    return s;
}

// ---------------- weight loader ----------------
__device__ __forceinline__ G4 ldWG4(const unsigned short* __restrict__ m, int g, int ro, int g4) {
    const unsigned short* p = m + (size_t)(g * 112 + ro) * 128 + g4 * 8;
    G4 w;
    w.a = *(const frag8*)p;        w.b = *(const frag8*)(p + 32);
    w.c = *(const frag8*)(p + 64); w.d = *(const frag8*)(p + 96);
    return w;
}

__device__ __forceinline__ void logits_one(const unsigned short* sm, int H2buf,
        const G4& O0, const G4& O1, int grp, int lt,
        float* __restrict__ out, int rbase, int c16, int g4) {
    G4 L = ldSG4(sm, H2buf, grp, c16, g4);
    f32x4 a0 = {0.f, 0.f, 0.f, 0.f}, a1 = a0;
    a0 = dot4(O0, L, a0);
    a1 = dot4(O1, L, a1);
    float* po = out + (size_t)(rbase + grp * 16 + c16) * 420 + lt * 20;
    *(f32x4*)(po + g4 * 4) = a0;           // vocab 4*g4 .. +4
    if (g4 == 0) *(f32x4*)(po + 16) = a1;  // vocab 16..19
}

// ---------------- one GRU layer phase: X pass + G pass, 1 barrier ----------------
__device__ __forceinline__ void gru_phase(unsigned short* sm, int HS, int HDp, int HDq,
    const unsigned short* __restrict__ wih, const unsigned short* __restrict__ whh,
    const G4* O, int H2buf, int lt, float* __restrict__ out, int rbase,
    bool owner, bool vald, int c16, int g4, int ro, int nbase)
{
    __syncthreads();                              // phase start: prev writes visible
    if (owner) {
        // ---- pass X: gx = S @ wih^T (3 gates), parked in f32 accs ----
        G4 Wi0 = ldWG4(wih, 0, ro, g4), Wi1 = ldWG4(wih, 1, ro, g4), Wi2 = ldWG4(wih, 2, ro, g4);
        pin(Wi0); pin(Wi1); pin(Wi2);
        f32x4 px0[NGRP], px1[NGRP], px2[NGRP];
#pragma unroll
        for (int grp = 0; grp < NGRP; ++grp) {
            G4 S = ldSG4(sm, HS, grp, c16, g4);
            f32x4 z = {0.f, 0.f, 0.f, 0.f};
            px0[grp] = dot4(Wi0, S, z);
            px1[grp] = dot4(Wi1, S, z);
            px2[grp] = dot4(Wi2, S, z);
        }
        // ---- pass G: gh = D @ whh^T, combine, write h -> HDq (race-free) ----
        G4 Wh0 = ldWG4(whh, 0, ro, g4), Wh1 = ldWG4(whh, 1, ro, g4), Wh2 = ldWG4(whh, 2, ro, g4);
        pin(Wh0); pin(Wh1); pin(Wh2);
#pragma unroll
        for (int grp = 0; grp < NGRP; ++grp) {
            G4 D = ldSG4(sm, HDp, grp, c16, g4);
            f32x4 z = {0.f, 0.f, 0.f, 0.f};
            f32x4 hr = dot4(Wh0, D, z);
            f32x4 hz = dot4(Wh1, D, z);
            f32x4 hh = dot4(Wh2, D, z);
            frag4 hold = *(const frag4*)(sm + hsw(HDp, grp, c16, nbase));
            frag4 hn;
#pragma unroll
            for (int j = 0; j < 4; ++j) {
                float r  = __builtin_amdgcn_rcpf(1.f + __builtin_amdgcn_exp2f(-(px0[grp][j] + hr[j])));
                float zz = __builtin_amdgcn_rcpf(1.f + __builtin_amdgcn_exp2f(-(px1[grp][j] + hz[j])));
                float y  = px2[grp][j] + r * hh[j];
                float nn = 1.f - 2.f * __builtin_amdgcn_rcpf(1.f + __builtin_amdgcn_exp2f(y));
                float ho = b2f((unsigned short)hold[j]);
                hn[j] = (short)f2b(nn + zz * (ho - nn));
            }
            if (vald) *(frag4*)(sm + hsw(HDq, grp, c16, nbase)) = hn;
        }
    } else if (O != nullptr && lt >= 0) {
#pragma unroll 1
        for (int grp = 0; grp < NGRP; ++grp)
            logits_one(sm, H2buf, O[0], O[1], grp, lt, out, rbase, c16, g4);
    }
}

// ---------------- main kernel ----------------
__global__ void __launch_bounds__(NTHR, 2) rnn_kernel(
    const float* __restrict__ enc,
    const float* __restrict__ b_proj,
    const unsigned short* __restrict__ wp,
    float* __restrict__ out)
{
    __shared__ unsigned short sm[SMEM_U16];       // 112 KB static -> 1 block/CU
    const int tid  = threadIdx.x;
    const int lane = tid & 63;
    const int wid  = tid >> 6;
    const int c16  = lane & 15;
    const int g4   = lane >> 4;
    const int rbase = blockIdx.x * ROWS_PB;
    const bool owner = (wid < 7);
    const int tw    = owner ? wid : 0;
    const int ro    = tw * 16 + c16;
    const int nbase = tw * 16 + g4 * 4;
    const bool vald = owner && (nbase < 100);

    // ---- init LDS: zeros, logical col 100 = 1.0 (bias), both h copies ----
    for (int i = tid; i < SMEM_U16; i += NTHR) {
        int r  = (i >> 7) & 63;
        int cu = i & 127;
        int lcol = ((((cu >> 3) ^ (r & 7)) << 3) | (cu & 7));
        sm[i] = (lcol == 100) ? (unsigned short)0x3F80 : (unsigned short)0;
    }

    // ---- wave 7: persistent w_out fragments ----
    G4 O[2];
    if (!owner) {
        O[0] = ldWG4(wp + OFF_OUT, 0, c16, g4);
        O[1] = ldWG4(wp + OFF_OUT, 0, 16 + c16, g4);
        pin(O[0]); pin(O[1]);
    }
    __syncthreads();

    // ---- prologue: x0 = enc @ w_proj^T + b_proj -> X0 (K=128 exact) ----
    if (owner) {
        G4 P = ldWG4(wp + OFF_PROJ, 0, ro, g4);
        f32x4 bp = {0.f, 0.f, 0.f, 0.f};
        if (vald) bp = *(const f32x4*)(b_proj + nbase);
#pragma unroll 1
        for (int grp = 0; grp < NGRP; ++grp) {
            const float* ep = enc + (size_t)(rbase + grp * 16 + c16) * 128 + g4 * 8;
            G4 E;
            {
                frag8 e0, e1, e2, e3;
#pragma unroll
                for (int j = 0; j < 8; ++j) {
                    e0[j] = (short)f2b(ep[j]);      e1[j] = (short)f2b(ep[32 + j]);
                    e2[j] = (short)f2b(ep[64 + j]); e3[j] = (short)f2b(ep[96 + j]);
                }
                E.a = e0; E.b = e1; E.c = e2; E.d = e3;
            }
            f32x4 acc = dot4(P, E, bp);
            if (vald) {
                frag4 xv;
#pragma unroll
                for (int j = 0; j < 4; ++j) xv[j] = (short)f2b(acc[j]);
                *(frag4*)(sm + hsw(X0_OFF, grp, c16, nbase)) = xv;
            }
        }
    }
    // (first phase's barrier provides the needed sync)

    // ---- time loop: read H[p], write H[1-p]; wave 7 logits(t-1) in phase 0 ----
#pragma unroll 1
    for (int t = 0; t < 21; ++t) {
        const int p = t & 1, q = 1 - p;
        gru_phase(sm, X0_OFF,    HB(0, p), HB(0, q), wp + OFF_IH0, wp + OFF_HH0,
                  O, HB(2, p), t - 1, out, rbase, owner, vald, c16, g4, ro, nbase);
        gru_phase(sm, HB(0, q),  HB(1, p), HB(1, q), wp + OFF_IH1, wp + OFF_HH1,
                  nullptr, 0, -1, out, rbase, owner, vald, c16, g4, ro, nbase);
        gru_phase(sm, HB(1, q),  HB(2, p), HB(2, q), wp + OFF_IH2, wp + OFF_HH2,
                  nullptr, 0, -1, out, rbase, owner, vald, c16, g4, ro, nbase);
    }

    // ---- tail: logits for t=20 (wave 7); t=20 wrote H2 copy 1 ----
    __syncthreads();
    if (!owner) {
#pragma unroll 1
        for (int grp = 0; grp < NGRP; ++grp)
            logits_one(sm, HB(2, 1), O[0], O[1], grp, 20, out, rbase, c16, g4);
    }
}

extern "C" void kernel_launch(void* const* d_in, const int* in_sizes, int n_in,
                              void* d_out, int out_size, void* d_ws, size_t ws_size,
                              hipStream_t stream) {
    const float* enc    = (const float*)d_in[0];
    const float* w_proj = (const float*)d_in[1];
    const float* b_proj = (const float*)d_in[2];
    const float* wih0   = (const float*)d_in[3];
    const float* whh0   = (const float*)d_in[4];
    const float* bih0   = (const float*)d_in[5];
    const float* bhh0   = (const float*)d_in[6];
    const float* wih1   = (const float*)d_in[7];
    const float* whh1   = (const float*)d_in[8];
    const float* bih1   = (const float*)d_in[9];
    const float* bhh1   = (const float*)d_in[10];
    const float* wih2   = (const float*)d_in[11];
    const float* whh2   = (const float*)d_in[12];
    const float* bih2   = (const float*)d_in[13];
    const float* bhh2   = (const float*)d_in[14];
    const float* w_out  = (const float*)d_in[15];
    const float* b_out  = (const float*)d_in[16];
    unsigned short* wpd = (unsigned short*)d_ws;   // 552,960 B used
    float* out          = (float*)d_out;

    prep_kernel<<<(WP_TOTAL + 255) / 256, 256, 0, stream>>>(
        w_proj, wih0, bih0, whh0, bhh0, wih1, bih1, whh1, bhh1,
        wih2, bih2, whh2, bhh2, w_out, b_out, wpd);

    rnn_kernel<<<NBLK, NTHR, 0, stream>>>(enc, b_proj, wpd, out);
}

// Round 11
// 592.450 us; speedup vs baseline: 1.3319x; 1.3319x over previous
//
#include <hip/hip_runtime.h>

// DecoderRNN v11: 3-layer GRU, B=32768, H=100, 21 steps, VOCAB=20.
// v9 shell (8 waves x 128 rows, grid 256, static 128KB LDS, 63 phases,
// 2 barriers/phase, exp2 activations, pinned per-pass weights) with the
// 3-gate passes restructured into TWO read-once passes:
//   pass G (post-B0): read D once/grp, gh for all 3 gates -> park
//                     (gh_r, gh_z packed bf16; gh_n f32)
//   pass X (post-B1): read S once/grp + own hold, gx by MFMA, combine,
//                     write h IN PLACE (D reads all done at B1).
// LDS traffic/phase drops ~3x vs v9 (the measured wall: ~1.34MB/CU/phase,
// 9.4e7 conflict-cycles). Phase count and shell unchanged (v10 lesson:
// per-phase overhead dominates when work/phase shrinks).

#define NTHR 512
#define NBLK 256
#define ROWS_PB 128

// wp (u16) offsets
#define OFF_PROJ 0                 // [112][128]
#define OFF_IH0  14336             // each [336][128]: row g*112+nn, col 100 = bias
#define OFF_HH0  57344
#define OFF_IH1  100352
#define OFF_HH1  143360
#define OFF_IH2  186368
#define OFF_HH2  229376
#define OFF_OUT  272384            // [32][128], col 100 = b_out (rows 20..31 zero)
#define WP_TOTAL 276480

// LDS (u16): 4 buffers [128][128], 16B-chunk XOR swizzle
#define X0_OFF   0
#define H0_OFF   16384
#define H1_OFF   32768
#define H2_OFF   49152
#define SMEM_U16 65536             // 131072 B static

using frag8 = __attribute__((ext_vector_type(8))) short;
using frag4 = __attribute__((ext_vector_type(4))) short;
using f32x4 = __attribute__((ext_vector_type(4))) float;

struct G4 { frag8 a, b, c, d; };

__device__ __forceinline__ unsigned short f2b(float f) {
    union { float f; unsigned u; } v; v.f = f;
    unsigned r = v.u + 0x7FFF + ((v.u >> 16) & 1);   // RNE
    return (unsigned short)(r >> 16);
}
__device__ __forceinline__ float b2f(unsigned short b) {
    union { unsigned u; float f; } v; v.u = ((unsigned)b) << 16; return v.f;
}

__device__ __forceinline__ f32x4 mfma32(frag8 a, frag8 b, f32x4 c) {
    return __builtin_amdgcn_mfma_f32_16x16x32_bf16(a, b, c, 0, 0, 0);
}
__device__ __forceinline__ f32x4 dot4(const G4& w, const G4& s, f32x4 acc) {
    acc = mfma32(w.a, s.a, acc); acc = mfma32(w.b, s.b, acc);
    acc = mfma32(w.c, s.c, acc); return mfma32(w.d, s.d, acc);
}
// keep a loaded fragment opaque -> compiler cannot rematerialize its load
__device__ __forceinline__ void pin(G4& w) {
    asm volatile("" : "+v"(w.a), "+v"(w.b), "+v"(w.c), "+v"(w.d));
}

// ---------------- weight prep: f32 -> bf16, padded, bias col 100, prescaled ----
__global__ void prep_kernel(const float* __restrict__ w_proj,
    const float* __restrict__ wih0, const float* __restrict__ bih0,
    const float* __restrict__ whh0, const float* __restrict__ bhh0,
    const float* __restrict__ wih1, const float* __restrict__ bih1,
    const float* __restrict__ whh1, const float* __restrict__ bhh1,
    const float* __restrict__ wih2, const float* __restrict__ bih2,
    const float* __restrict__ whh2, const float* __restrict__ bhh2,
    const float* __restrict__ w_out, const float* __restrict__ b_out,
    unsigned short* __restrict__ dst)
{
    const float LOG2E  = 1.4426950408889634f;
    const float LOG2E2 = 2.8853900817779268f;
    int idx = blockIdx.x * 256 + threadIdx.x;
    if (idx >= WP_TOTAL) return;
    float v = 0.f;
    if (idx < OFF_IH0) {
        int n = idx >> 7, k = idx & 127;
        if (n < 100) v = w_proj[n * 128 + k];
    } else if (idx < OFF_OUT) {
        int r = idx - OFF_IH0;
        int mi = r / 43008;
        int e  = r - mi * 43008;
        int n = e >> 7, k = e & 127;
        int g = n / 112, nn = n - g * 112;
        if (nn < 100) {
            const float* W; const float* Bv;
            switch (mi) {
                case 0: W = wih0; Bv = bih0; break;
                case 1: W = whh0; Bv = bhh0; break;
                case 2: W = wih1; Bv = bih1; break;
                case 3: W = whh1; Bv = bhh1; break;
                case 4: W = wih2; Bv = bih2; break;
                default: W = whh2; Bv = bhh2; break;
            }
            if (k < 100) v = W[(g * 100 + nn) * 100 + k];
            else if (k == 100) v = Bv[g * 100 + nn];
            v *= (g == 2) ? LOG2E2 : LOG2E;       // exp2-form activations
        }
    } else {
        int e = idx - OFF_OUT;
        int n = e >> 7, k = e & 127;
        if (n < 20) {
            if (k < 100) v = w_out[n * 100 + k];
            else if (k == 100) v = b_out[n];
        }
    }
    dst[idx] = f2b(v);
}

// ---------------- LDS helpers (swizzled) ----------------
// logical u16 col cu of row r stored at 8-u16 chunk (cu>>3) ^ (r&7)
__device__ __forceinline__ int hsw(int buf, int grp, int r, int cu) {
    int row = grp * 16 + r;
    return buf + row * 128 + ((((cu >> 3) ^ (row & 7)) << 3) | (cu & 7));
}
__device__ __forceinline__ G4 ldSG4(const unsigned short* sm, int buf, int grp, int c16, int g4) {
    const unsigned short* p = sm + buf + (grp * 16 + c16) * 128;
    int x = c16 & 7;
    G4 s;
    s.a = *(const frag8*)(p + ((g4 ^ x) << 3));
    s.b = *(const frag8*)(p + (((4 + g4) ^ x) << 3));
    s.c = *(const frag8*)(p + (((8 + g4) ^ x) << 3));
    s.d = *(const frag8*)(p + (((12 + g4) ^ x) << 3));
    return s;
}

// ---------------- weight loader ----------------
__device__ __forceinline__ G4 ldWG4(const unsigned short* __restrict__ m, int g, int ro, int g4) {
    const unsigned short* p = m + (size_t)(g * 112 + ro) * 128 + g4 * 8;
    G4 w;
    w.a = *(const frag8*)p;        w.b = *(const frag8*)(p + 32);
    w.c = *(const frag8*)(p + 64); w.d = *(const frag8*)(p + 96);
    return w;
}

__device__ __forceinline__ void logits_one(const unsigned short* sm,
        const G4& O0, const G4& O1, int grp, int lt,
        float* __restrict__ out, int rbase, int c16, int g4) {
    G4 L = ldSG4(sm, H2_OFF, grp, c16, g4);
    f32x4 a0 = {0.f, 0.f, 0.f, 0.f}, a1 = a0;
    a0 = dot4(O0, L, a0);
    a1 = dot4(O1, L, a1);
    float* po = out + (size_t)(rbase + grp * 16 + c16) * 420 + lt * 20;
    *(f32x4*)(po + g4 * 4) = a0;           // vocab 4*g4 .. +4
    if (g4 == 0) *(f32x4*)(po + 16) = a1;  // vocab 16..19
}

// ---------------- one GRU layer phase: pass G + pass X, 2 barriers ----------------
template<bool PH0>
__device__ __forceinline__ void gru_phase(unsigned short* sm, int HS, int HD,
    const unsigned short* __restrict__ wih, const unsigned short* __restrict__ whh,
    const G4* O, int lt, float* __restrict__ out, int rbase,
    bool owner, bool vald, int c16, int g4, int ro, int nbase)
{
    // Wh loads issue pre-B0: L2 latency hides under the barrier wait
    G4 Wh0, Wh1, Wh2;
    if (owner) {
        Wh0 = ldWG4(whh, 0, ro, g4); Wh1 = ldWG4(whh, 1, ro, g4); Wh2 = ldWG4(whh, 2, ro, g4);
        pin(Wh0); pin(Wh1); pin(Wh2);
    }
    __syncthreads();                              // B0: prev-phase writes visible
    frag4 ghr[8], ghz[8];
    f32x4 ghn[8];
    G4 Wi0, Wi1, Wi2;
    if (owner) {
        // ---- pass G: read D once per grp, all 3 gh gates, park ----
#pragma unroll
        for (int grp = 0; grp < 8; ++grp) {
            G4 D = ldSG4(sm, HD, grp, c16, g4);
            f32x4 z = {0.f, 0.f, 0.f, 0.f};
            f32x4 hr = dot4(Wh0, D, z);
            f32x4 hz = dot4(Wh1, D, z);
            ghn[grp] = dot4(Wh2, D, z);
#pragma unroll
            for (int j = 0; j < 4; ++j) {
                ghr[grp][j] = (short)f2b(hr[j]);
                ghz[grp][j] = (short)f2b(hz[j]);
            }
        }
        // Wi loads pre-B1: overlap with other waves finishing pass G
        Wi0 = ldWG4(wih, 0, ro, g4); Wi1 = ldWG4(wih, 1, ro, g4); Wi2 = ldWG4(wih, 2, ro, g4);
        pin(Wi0); pin(Wi1); pin(Wi2);
    } else if (PH0 && lt >= 0) {
#pragma unroll 1
        for (int grp = 0; grp < 8; ++grp)
            logits_one(sm, O[0], O[1], grp, lt, out, rbase, c16, g4);
    }
    __syncthreads();                              // B1: all D reads done
    if (owner) {
        // ---- pass X: read S once per grp + own hold, combine, write in place ----
#pragma unroll
        for (int grp = 0; grp < 8; ++grp) {
            G4 S = ldSG4(sm, HS, grp, c16, g4);
            f32x4 z = {0.f, 0.f, 0.f, 0.f};
            f32x4 xr = dot4(Wi0, S, z);
            f32x4 xz = dot4(Wi1, S, z);
            f32x4 xn = dot4(Wi2, S, z);
            frag4 hold = *(const frag4*)(sm + hsw(HD, grp, c16, nbase));
            frag4 hn;
#pragma unroll
            for (int j = 0; j < 4; ++j) {
                float r  = __builtin_amdgcn_rcpf(1.f + __builtin_amdgcn_exp2f(-(xr[j] + b2f((unsigned short)ghr[grp][j]))));
                float zz = __builtin_amdgcn_rcpf(1.f + __builtin_amdgcn_exp2f(-(xz[j] + b2f((unsigned short)ghz[grp][j]))));
                float y  = xn[j] + r * ghn[grp][j];
                float nn = 1.f - 2.f * __builtin_amdgcn_rcpf(1.f + __builtin_amdgcn_exp2f(y));
                float ho = b2f((unsigned short)hold[j]);
                hn[j] = (short)f2b(nn + zz * (ho - nn));
            }
            if (vald) *(frag4*)(sm + hsw(HD, grp, c16, nbase)) = hn;
        }
    }
}

// ---------------- main kernel ----------------
__global__ void __launch_bounds__(NTHR, 2) rnn_kernel(
    const float* __restrict__ enc,
    const float* __restrict__ b_proj,
    const unsigned short* __restrict__ wp,
    float* __restrict__ out)
{
    __shared__ unsigned short sm[SMEM_U16];       // 128 KB static
    const int tid  = threadIdx.x;
    const int lane = tid & 63;
    const int wid  = tid >> 6;
    const int c16  = lane & 15;
    const int g4   = lane >> 4;
    const int rbase = blockIdx.x * ROWS_PB;
    const bool owner = (wid < 7);
    const int tw    = owner ? wid : 0;
    const int ro    = tw * 16 + c16;
    const int nbase = tw * 16 + g4 * 4;
    const bool vald = owner && (nbase < 100);

    // ---- init LDS: zeros, logical col 100 = 1.0 (bias) ----
    for (int i = tid; i < SMEM_U16; i += NTHR) {
        int r  = (i >> 7) & 127;
        int cu = i & 127;
        int lcol = ((((cu >> 3) ^ (r & 7)) << 3) | (cu & 7));
        sm[i] = (lcol == 100) ? (unsigned short)0x3F80 : (unsigned short)0;
    }

    // ---- wave 7: persistent w_out fragments ----
    G4 O[2];
    if (!owner) {
        O[0] = ldWG4(wp + OFF_OUT, 0, c16, g4);
        O[1] = ldWG4(wp + OFF_OUT, 0, 16 + c16, g4);
        pin(O[0]); pin(O[1]);
    }
    __syncthreads();

    // ---- prologue: x0 = enc @ w_proj^T + b_proj -> X0 (K=128 exact) ----
    if (owner) {
        G4 P = ldWG4(wp + OFF_PROJ, 0, ro, g4);
        f32x4 bp = {0.f, 0.f, 0.f, 0.f};
        if (vald) bp = *(const f32x4*)(b_proj + nbase);
#pragma unroll 1
        for (int grp = 0; grp < 8; ++grp) {
            const float* ep = enc + (size_t)(rbase + grp * 16 + c16) * 128 + g4 * 8;
            G4 E;
            {
                frag8 e0, e1, e2, e3;
#pragma unroll
                for (int j = 0; j < 8; ++j) {
                    e0[j] = (short)f2b(ep[j]);      e1[j] = (short)f2b(ep[32 + j]);
                    e2[j] = (short)f2b(ep[64 + j]); e3[j] = (short)f2b(ep[96 + j]);
                }
                E.a = e0; E.b = e1; E.c = e2; E.d = e3;
            }
            f32x4 acc = dot4(P, E, bp);
            if (vald) {
                frag4 xv;
#pragma unroll
                for (int j = 0; j < 4; ++j) xv[j] = (short)f2b(acc[j]);
                *(frag4*)(sm + hsw(X0_OFF, grp, c16, nbase)) = xv;
            }
        }
    }
    // (first phase's B0 provides the needed sync)

    // ---- time loop: three phases; wave 7 logits(t-1) during phase 0 ----
#pragma unroll 1
    for (int t = 0; t < 21; ++t) {
        gru_phase<true >(sm, X0_OFF, H0_OFF, wp + OFF_IH0, wp + OFF_HH0,
                         O, t - 1, out, rbase, owner, vald, c16, g4, ro, nbase);
        gru_phase<false>(sm, H0_OFF, H1_OFF, wp + OFF_IH1, wp + OFF_HH1,
                         O, -1, out, rbase, owner, vald, c16, g4, ro, nbase);
        gru_phase<false>(sm, H1_OFF, H2_OFF, wp + OFF_IH2, wp + OFF_HH2,
                         O, -1, out, rbase, owner, vald, c16, g4, ro, nbase);
    }

    // ---- tail: logits for t=20 (wave 7) ----
    __syncthreads();
    if (!owner) {
#pragma unroll 1
        for (int grp = 0; grp < 8; ++grp)
            logits_one(sm, O[0], O[1], grp, 20, out, rbase, c16, g4);
    }
}

extern "C" void kernel_launch(void* const* d_in, const int* in_sizes, int n_in,
                              void* d_out, int out_size, void* d_ws, size_t ws_size,
                              hipStream_t stream) {
    const float* enc    = (const float*)d_in[0];
    const float* w_proj = (const float*)d_in[1];
    const float* b_proj = (const float*)d_in[2];
    const float* wih0   = (const float*)d_in[3];
    const float* whh0   = (const float*)d_in[4];
    const float* bih0   = (const float*)d_in[5];
    const float* bhh0   = (const float*)d_in[6];
    const float* wih1   = (const float*)d_in[7];
    const float* whh1   = (const float*)d_in[8];
    const float* bih1   = (const float*)d_in[9];
    const float* bhh1   = (const float*)d_in[10];
    const float* wih2   = (const float*)d_in[11];
    const float* whh2   = (const float*)d_in[12];
    const float* bih2   = (const float*)d_in[13];
    const float* bhh2   = (const float*)d_in[14];
    const float* w_out  = (const float*)d_in[15];
    const float* b_out  = (const float*)d_in[16];
    unsigned short* wpd = (unsigned short*)d_ws;   // 552,960 B used
    float* out          = (float*)d_out;

    prep_kernel<<<(WP_TOTAL + 255) / 256, 256, 0, stream>>>(
        w_proj, wih0, bih0, whh0, bhh0, wih1, bih1, whh1, bhh1,
        wih2, bih2, whh2, bhh2, w_out, b_out, wpd);

    rnn_kernel<<<NBLK, NTHR, 0, stream>>>(enc, b_proj, wpd, out);
}